// Round 1
// baseline (2784.730 us; speedup 1.0000x reference)
//
#include <hip/hip_runtime.h>

#define HDIM 64

// ---------------- CSR build helpers ----------------

__global__ void k_zero2(int* __restrict__ a, int na, int* __restrict__ b, int nb) {
  int i = blockIdx.x * blockDim.x + threadIdx.x;
  int stride = gridDim.x * blockDim.x;
  for (int j = i; j < na; j += stride) a[j] = 0;
  for (int j = i; j < nb; j += stride) b[j] = 0;
}

__global__ void k_count(const int* __restrict__ dum, const int* __restrict__ dmu,
                        int* __restrict__ cm, int* __restrict__ cu, int E) {
  int i = blockIdx.x * blockDim.x + threadIdx.x;
  int stride = gridDim.x * blockDim.x;
  for (int e = i; e < E; e += stride) {
    atomicAdd(&cm[dum[e]], 1);
    atomicAdd(&cu[dmu[e]], 1);
  }
}

// block b sums in[b*1024 .. b*1024+1023] -> part[b]
__global__ void k_block_sum(const int* __restrict__ in, int* __restrict__ part, int n) {
  __shared__ int s[256];
  int b = blockIdx.x, t = threadIdx.x;
  int base = b * 1024;
  int v = 0;
  for (int i = t; i < 1024; i += 256) {
    int idx = base + i;
    if (idx < n) v += in[idx];
  }
  s[t] = v;
  __syncthreads();
  for (int o = 128; o > 0; o >>= 1) {
    if (t < o) s[t] += s[t + o];
    __syncthreads();
  }
  if (t == 0) part[b] = s[0];
}

// single block, nb <= 256: exclusive scan of part[]
__global__ void k_scan_part(int* __restrict__ part, int nb) {
  __shared__ int s[256];
  int t = threadIdx.x;
  int v = (t < nb) ? part[t] : 0;
  s[t] = v;
  __syncthreads();
  for (int o = 1; o < 256; o <<= 1) {
    int u = (t >= o) ? s[t - o] : 0;
    __syncthreads();
    s[t] += u;
    __syncthreads();
  }
  if (t < nb) part[t] = s[t] - v;  // exclusive
}

// block b: exclusive scan of its 1024-chunk + part[b] offset -> out
__global__ void k_scan_final(const int* __restrict__ in, const int* __restrict__ part,
                             int* __restrict__ out, int n) {
  __shared__ int s[256];
  int b = blockIdx.x, t = threadIdx.x;
  int base = b * 1024 + t * 4;
  int a[4];
#pragma unroll
  for (int i = 0; i < 4; i++) a[i] = (base + i < n) ? in[base + i] : 0;
  int tsum = a[0] + a[1] + a[2] + a[3];
  s[t] = tsum;
  __syncthreads();
  for (int o = 1; o < 256; o <<= 1) {
    int u = (t >= o) ? s[t - o] : 0;
    __syncthreads();
    s[t] += u;
    __syncthreads();
  }
  int excl = s[t] - tsum + part[b];
#pragma unroll
  for (int i = 0; i < 4; i++) {
    if (base + i < n) out[base + i] = excl;
    excl += a[i];
  }
}

__global__ void k_settotal(int* __restrict__ pm, int* __restrict__ pu, int E) {
  if (threadIdx.x == 0 && blockIdx.x == 0) { *pm = E; *pu = E; }
}

__global__ void k_fill(const int* __restrict__ sum_, const int* __restrict__ dum,
                       const int* __restrict__ smu, const int* __restrict__ dmu,
                       const int* __restrict__ offm, const int* __restrict__ offu,
                       int* __restrict__ curm, int* __restrict__ curu,
                       int* __restrict__ csrm, int* __restrict__ csru, int E) {
  int i = blockIdx.x * blockDim.x + threadIdx.x;
  int stride = gridDim.x * blockDim.x;
  for (int e = i; e < E; e += stride) {
    int d = dum[e];
    int p = atomicAdd(&curm[d], 1);
    csrm[offm[d] + p] = sum_[e];
    int d2 = dmu[e];
    int p2 = atomicAdd(&curu[d2], 1);
    csru[offu[d2] + p2] = smu[e];
  }
}

// ---------------- fused SAGE conv: mean-agg + [agg,xdst]@[Wl;Wr] + b (+relu) ----------------
// one 64-lane wave per dst node, lane = output feature j
__global__ __launch_bounds__(256) void k_sage(const float* __restrict__ xsrc,
                                              const float* __restrict__ xdst,
                                              const int* __restrict__ offs,
                                              const int* __restrict__ csr,
                                              const float* __restrict__ Wl,
                                              const float* __restrict__ Wr,
                                              const float* __restrict__ bias,
                                              float* __restrict__ out,
                                              int n_dst, int do_relu) {
  __shared__ float sWl[HDIM * HDIM];
  __shared__ float sWr[HDIM * HDIM];
  int t = threadIdx.x;
  for (int i = t; i < HDIM * HDIM; i += 256) {
    sWl[i] = Wl[i];
    sWr[i] = Wr[i];
  }
  __syncthreads();

  int lane = t & 63;
  int wid = (blockIdx.x * blockDim.x + t) >> 6;
  int nwaves = (gridDim.x * blockDim.x) >> 6;
  float bj = bias[lane];

  for (int node = wid; node < n_dst; node += nwaves) {
    int beg = offs[node];
    int end = offs[node + 1];
    float agg = 0.f;
    for (int e = beg; e < end; ++e) {
      int s = csr[e];
      agg += xsrc[(size_t)s * HDIM + lane];
    }
    int deg = end - beg;
    agg *= (deg > 0) ? (1.0f / (float)deg) : 0.f;
    float xd = xdst[(size_t)node * HDIM + lane];
    float acc = bj;
#pragma unroll
    for (int h = 0; h < HDIM; ++h) {
      float a = __shfl(agg, h);
      float d = __shfl(xd, h);
      acc += a * sWl[h * HDIM + lane];
      acc += d * sWr[h * HDIM + lane];
    }
    if (do_relu) acc = fmaxf(acc, 0.f);
    out[(size_t)node * HDIM + lane] = acc;
  }
}

// ---------------- launch ----------------

extern "C" void kernel_launch(void* const* d_in, const int* in_sizes, int n_in,
                              void* d_out, int out_size, void* d_ws, size_t ws_size,
                              hipStream_t stream) {
  const int NU = in_sizes[0];
  const int NM = in_sizes[1];
  const int E  = in_sizes[2];

  const int* src_um = (const int*)d_in[2];
  const int* dst_um = (const int*)d_in[3];
  const int* src_mu = (const int*)d_in[4];
  const int* dst_mu = (const int*)d_in[5];
  const float* user_table  = (const float*)d_in[6];
  const float* movie_table = (const float*)d_in[7];
  const float* Wl1_um = (const float*)d_in[8];
  const float* Wr1_um = (const float*)d_in[9];
  const float* Wl1_mu = (const float*)d_in[10];
  const float* Wr1_mu = (const float*)d_in[11];
  const float* Wl2_um = (const float*)d_in[12];
  const float* Wr2_um = (const float*)d_in[13];
  const float* Wl2_mu = (const float*)d_in[14];
  const float* Wr2_mu = (const float*)d_in[15];
  const float* b1_um = (const float*)d_in[16];
  const float* b1_mu = (const float*)d_in[17];
  const float* b2_um = (const float*)d_in[18];
  const float* b2_mu = (const float*)d_in[19];

  float* out_u2 = (float*)d_out;                       // [NU,64]
  float* out_m2 = (float*)d_out + (size_t)NU * HDIM;   // [NM,64]

  // workspace carve (256B aligned)
  char* ws = (char*)d_ws;
  size_t off = 0;
  auto carve = [&](size_t bytes) -> char* {
    char* p = ws + off;
    off = (off + bytes + 255) & ~(size_t)255;
    return p;
  };
  int* offm = (int*)carve((size_t)(NM + 1) * 4);
  int* offu = (int*)carve((size_t)(NU + 1) * 4);
  int* curm = (int*)carve((size_t)NM * 4);
  int* curu = (int*)carve((size_t)NU * 4);
  int* part = (int*)carve(256 * 4);
  int* csrm = (int*)carve((size_t)E * 4);  // user srcs bucketed by movie
  int* csru = (int*)carve((size_t)E * 4);  // movie srcs bucketed by user
  float* m1 = (float*)carve((size_t)NM * HDIM * 4);
  float* u1 = (float*)carve((size_t)NU * HDIM * 4);
  (void)ws_size;

  const int TB = 256;
  int gridE = 2048;

  // 1) counts
  k_zero2<<<512, TB, 0, stream>>>(curm, NM, curu, NU);
  k_count<<<gridE, TB, 0, stream>>>(dst_um, dst_mu, curm, curu, E);

  // 2) exclusive scans -> offsets
  int nbm = (NM + 1023) / 1024;
  int nbu = (NU + 1023) / 1024;
  k_block_sum<<<nbm, TB, 0, stream>>>(curm, part, NM);
  k_scan_part<<<1, TB, 0, stream>>>(part, nbm);
  k_scan_final<<<nbm, TB, 0, stream>>>(curm, part, offm, NM);
  k_block_sum<<<nbu, TB, 0, stream>>>(curu, part, NU);
  k_scan_part<<<1, TB, 0, stream>>>(part, nbu);
  k_scan_final<<<nbu, TB, 0, stream>>>(curu, part, offu, NU);
  k_settotal<<<1, 64, 0, stream>>>(offm + NM, offu + NU, E);

  // 3) fill CSR
  k_zero2<<<512, TB, 0, stream>>>(curm, NM, curu, NU);
  k_fill<<<gridE, TB, 0, stream>>>(src_um, dst_um, src_mu, dst_mu,
                                   offm, offu, curm, curu, csrm, csru, E);

  // 4) layer 1 (relu)
  int gm = 2048, gu = 2048;
  k_sage<<<gm, TB, 0, stream>>>(user_table, movie_table, offm, csrm,
                                Wl1_um, Wr1_um, b1_um, m1, NM, 1);
  k_sage<<<gu, TB, 0, stream>>>(movie_table, user_table, offu, csru,
                                Wl1_mu, Wr1_mu, b1_mu, u1, NU, 1);

  // 5) layer 2 (no relu) -> outputs
  k_sage<<<gm, TB, 0, stream>>>(u1, m1, offm, csrm,
                                Wl2_um, Wr2_um, b2_um, out_m2, NM, 0);
  k_sage<<<gu, TB, 0, stream>>>(m1, u1, offu, csru,
                                Wl2_mu, Wr2_mu, b2_mu, out_u2, NU, 0);
}

// Round 2
// 1117.016 us; speedup vs baseline: 2.4930x; 2.4930x over previous
//
#include <hip/hip_runtime.h>

#define HDIM 64

// ---------------- CSR build helpers ----------------

__global__ void k_zero2(int* __restrict__ a, int na, int* __restrict__ b, int nb) {
  int i = blockIdx.x * blockDim.x + threadIdx.x;
  int stride = gridDim.x * blockDim.x;
  for (int j = i; j < na; j += stride) a[j] = 0;
  for (int j = i; j < nb; j += stride) b[j] = 0;
}

__global__ void k_count(const int* __restrict__ dum, const int* __restrict__ dmu,
                        int* __restrict__ cm, int* __restrict__ cu, int E) {
  int i = blockIdx.x * blockDim.x + threadIdx.x;
  int stride = gridDim.x * blockDim.x;
  for (int e = i; e < E; e += stride) {
    atomicAdd(&cm[dum[e]], 1);
    atomicAdd(&cu[dmu[e]], 1);
  }
}

// block b sums in[b*1024 .. b*1024+1023] -> part[b]
__global__ void k_block_sum(const int* __restrict__ in, int* __restrict__ part, int n) {
  __shared__ int s[256];
  int b = blockIdx.x, t = threadIdx.x;
  int base = b * 1024;
  int v = 0;
  for (int i = t; i < 1024; i += 256) {
    int idx = base + i;
    if (idx < n) v += in[idx];
  }
  s[t] = v;
  __syncthreads();
  for (int o = 128; o > 0; o >>= 1) {
    if (t < o) s[t] += s[t + o];
    __syncthreads();
  }
  if (t == 0) part[b] = s[0];
}

// single block, nb <= 256: exclusive scan of part[]
__global__ void k_scan_part(int* __restrict__ part, int nb) {
  __shared__ int s[256];
  int t = threadIdx.x;
  int v = (t < nb) ? part[t] : 0;
  s[t] = v;
  __syncthreads();
  for (int o = 1; o < 256; o <<= 1) {
    int u = (t >= o) ? s[t - o] : 0;
    __syncthreads();
    s[t] += u;
    __syncthreads();
  }
  if (t < nb) part[t] = s[t] - v;  // exclusive
}

// block b: exclusive scan of its 1024-chunk + part[b] offset -> out
__global__ void k_scan_final(const int* __restrict__ in, const int* __restrict__ part,
                             int* __restrict__ out, int n) {
  __shared__ int s[256];
  int b = blockIdx.x, t = threadIdx.x;
  int base = b * 1024 + t * 4;
  int a[4];
#pragma unroll
  for (int i = 0; i < 4; i++) a[i] = (base + i < n) ? in[base + i] : 0;
  int tsum = a[0] + a[1] + a[2] + a[3];
  s[t] = tsum;
  __syncthreads();
  for (int o = 1; o < 256; o <<= 1) {
    int u = (t >= o) ? s[t - o] : 0;
    __syncthreads();
    s[t] += u;
    __syncthreads();
  }
  int excl = s[t] - tsum + part[b];
#pragma unroll
  for (int i = 0; i < 4; i++) {
    if (base + i < n) out[base + i] = excl;
    excl += a[i];
  }
}

__global__ void k_settotal(int* __restrict__ pm, int* __restrict__ pu, int E) {
  if (threadIdx.x == 0 && blockIdx.x == 0) { *pm = E; *pu = E; }
}

__global__ void k_fill(const int* __restrict__ sum_, const int* __restrict__ dum,
                       const int* __restrict__ smu, const int* __restrict__ dmu,
                       const int* __restrict__ offm, const int* __restrict__ offu,
                       int* __restrict__ curm, int* __restrict__ curu,
                       int* __restrict__ csrm, int* __restrict__ csru, int E) {
  int i = blockIdx.x * blockDim.x + threadIdx.x;
  int stride = gridDim.x * blockDim.x;
  for (int e = i; e < E; e += stride) {
    int d = dum[e];
    int p = atomicAdd(&curm[d], 1);
    csrm[offm[d] + p] = sum_[e];
    int d2 = dmu[e];
    int p2 = atomicAdd(&curu[d2], 1);
    csru[offu[d2] + p2] = smu[e];
  }
}

// component select with compile-time c (folds under #pragma unroll)
__device__ __forceinline__ float f4c(const float4& v, int c) {
  return c == 0 ? v.x : c == 1 ? v.y : c == 2 ? v.z : v.w;
}

// ---------------- fused SAGE conv v2 ----------------
// 4 nodes per 64-lane wave; 16-lane group g owns node base+g.
// lane q (0..15) of a group holds feature columns 4q..4q+3 (float4).
// Weights staged in LDS, read as b128, h-rows split across groups
// (row range [16g,16g+16)) so Wl+Wr are read exactly once per 4 nodes.
__global__ __launch_bounds__(256) void k_sage(const float* __restrict__ xsrc,
                                              const float* __restrict__ xdst,
                                              const int* __restrict__ offs,
                                              const int* __restrict__ csr,
                                              const float* __restrict__ Wl,
                                              const float* __restrict__ Wr,
                                              const float* __restrict__ bias,
                                              float* __restrict__ out,
                                              int n_dst, int do_relu) {
  __shared__ float sWl[HDIM * HDIM];
  __shared__ float sWr[HDIM * HDIM];
  __shared__ float sAX[4][4][2][HDIM];  // [wave][group][a|x][feature]

  int t = threadIdx.x;
  {
    const float4* wl4 = (const float4*)Wl;
    const float4* wr4 = (const float4*)Wr;
    float4* swl4 = (float4*)sWl;
    float4* swr4 = (float4*)sWr;
    for (int i = t; i < HDIM * HDIM / 4; i += 256) {
      swl4[i] = wl4[i];
      swr4[i] = wr4[i];
    }
  }
  __syncthreads();

  int lane = t & 63;
  int w_in_b = t >> 6;
  int q = lane & 15;
  int g = lane >> 4;
  int wid = (blockIdx.x * blockDim.x + t) >> 6;
  int nwaves = (gridDim.x * blockDim.x) >> 6;
  float4 bj = *(const float4*)&bias[4 * q];

  for (int base = 4 * wid; base < n_dst; base += 4 * nwaves) {
    int myNode = base + g;
    bool valid = myNode < n_dst;
    int beg = valid ? offs[myNode] : 0;
    int end = valid ? offs[myNode + 1] : 0;

    // ---- gather + mean (per group, float4 per lane) ----
    float4 a = make_float4(0.f, 0.f, 0.f, 0.f);
    for (int bb = beg; bb < end; bb += 16) {
      int n = end - bb;
      n = n > 16 ? 16 : n;
      int idx = (q < n) ? csr[bb + q] : 0;
#pragma unroll 4
      for (int k = 0; k < n; ++k) {
        int s = __shfl(idx, 16 * g + k);
        const float4 v = *(const float4*)&xsrc[(size_t)s * HDIM + 4 * q];
        a.x += v.x; a.y += v.y; a.z += v.z; a.w += v.w;
      }
    }
    int deg = end - beg;
    float inv = deg > 0 ? 1.f / (float)deg : 0.f;
    a.x *= inv; a.y *= inv; a.z *= inv; a.w *= inv;

    float4 xd = make_float4(0.f, 0.f, 0.f, 0.f);
    if (valid) xd = *(const float4*)&xdst[(size_t)myNode * HDIM + 4 * q];

    // ---- stage a, xd rows into per-wave LDS scratch ----
    *(float4*)&sAX[w_in_b][g][0][4 * q] = a;
    *(float4*)&sAX[w_in_b][g][1][4 * q] = xd;
    // same-wave LDS ops are in-order; compiler inserts lgkmcnt waits.

    // ---- matmul: group g covers W rows [16g, 16g+16) for all 4 nodes ----
    float4 o0 = make_float4(0.f, 0.f, 0.f, 0.f);
    float4 o1 = o0, o2 = o0, o3 = o0;
#pragma unroll
    for (int hq = 0; hq < 4; ++hq) {
      int hbase = 16 * g + 4 * hq;
      float4 a0 = *(const float4*)&sAX[w_in_b][0][0][hbase];
      float4 a1 = *(const float4*)&sAX[w_in_b][1][0][hbase];
      float4 a2 = *(const float4*)&sAX[w_in_b][2][0][hbase];
      float4 a3 = *(const float4*)&sAX[w_in_b][3][0][hbase];
      float4 x0 = *(const float4*)&sAX[w_in_b][0][1][hbase];
      float4 x1 = *(const float4*)&sAX[w_in_b][1][1][hbase];
      float4 x2 = *(const float4*)&sAX[w_in_b][2][1][hbase];
      float4 x3 = *(const float4*)&sAX[w_in_b][3][1][hbase];
#pragma unroll
      for (int c = 0; c < 4; ++c) {
        int h = hbase + c;
        float4 wl = *(const float4*)&sWl[h * HDIM + 4 * q];
        float4 wr = *(const float4*)&sWr[h * HDIM + 4 * q];
        float av, xv;
        av = f4c(a0, c); xv = f4c(x0, c);
        o0.x += av * wl.x + xv * wr.x; o0.y += av * wl.y + xv * wr.y;
        o0.z += av * wl.z + xv * wr.z; o0.w += av * wl.w + xv * wr.w;
        av = f4c(a1, c); xv = f4c(x1, c);
        o1.x += av * wl.x + xv * wr.x; o1.y += av * wl.y + xv * wr.y;
        o1.z += av * wl.z + xv * wr.z; o1.w += av * wl.w + xv * wr.w;
        av = f4c(a2, c); xv = f4c(x2, c);
        o2.x += av * wl.x + xv * wr.x; o2.y += av * wl.y + xv * wr.y;
        o2.z += av * wl.z + xv * wr.z; o2.w += av * wl.w + xv * wr.w;
        av = f4c(a3, c); xv = f4c(x3, c);
        o3.x += av * wl.x + xv * wr.x; o3.y += av * wl.y + xv * wr.y;
        o3.z += av * wl.z + xv * wr.z; o3.w += av * wl.w + xv * wr.w;
      }
    }

    // ---- reduce partial outputs across the 4 groups (butterfly) ----
#pragma unroll
    for (int m = 16; m <= 32; m <<= 1) {
      o0.x += __shfl_xor(o0.x, m); o0.y += __shfl_xor(o0.y, m);
      o0.z += __shfl_xor(o0.z, m); o0.w += __shfl_xor(o0.w, m);
      o1.x += __shfl_xor(o1.x, m); o1.y += __shfl_xor(o1.y, m);
      o1.z += __shfl_xor(o1.z, m); o1.w += __shfl_xor(o1.w, m);
      o2.x += __shfl_xor(o2.x, m); o2.y += __shfl_xor(o2.y, m);
      o2.z += __shfl_xor(o2.z, m); o2.w += __shfl_xor(o2.w, m);
      o3.x += __shfl_xor(o3.x, m); o3.y += __shfl_xor(o3.y, m);
      o3.z += __shfl_xor(o3.z, m); o3.w += __shfl_xor(o3.w, m);
    }

    // group g stores node base+g (static select, no dynamic reg indexing)
    if (valid) {
      float4 r = (g == 0) ? o0 : (g == 1) ? o1 : (g == 2) ? o2 : o3;
      r.x += bj.x; r.y += bj.y; r.z += bj.z; r.w += bj.w;
      if (do_relu) {
        r.x = fmaxf(r.x, 0.f); r.y = fmaxf(r.y, 0.f);
        r.z = fmaxf(r.z, 0.f); r.w = fmaxf(r.w, 0.f);
      }
      *(float4*)&out[(size_t)myNode * HDIM + 4 * q] = r;
    }
  }
}

// ---------------- launch ----------------

extern "C" void kernel_launch(void* const* d_in, const int* in_sizes, int n_in,
                              void* d_out, int out_size, void* d_ws, size_t ws_size,
                              hipStream_t stream) {
  const int NU = in_sizes[0];
  const int NM = in_sizes[1];
  const int E  = in_sizes[2];

  const int* src_um = (const int*)d_in[2];
  const int* dst_um = (const int*)d_in[3];
  const int* src_mu = (const int*)d_in[4];
  const int* dst_mu = (const int*)d_in[5];
  const float* user_table  = (const float*)d_in[6];
  const float* movie_table = (const float*)d_in[7];
  const float* Wl1_um = (const float*)d_in[8];
  const float* Wr1_um = (const float*)d_in[9];
  const float* Wl1_mu = (const float*)d_in[10];
  const float* Wr1_mu = (const float*)d_in[11];
  const float* Wl2_um = (const float*)d_in[12];
  const float* Wr2_um = (const float*)d_in[13];
  const float* Wl2_mu = (const float*)d_in[14];
  const float* Wr2_mu = (const float*)d_in[15];
  const float* b1_um = (const float*)d_in[16];
  const float* b1_mu = (const float*)d_in[17];
  const float* b2_um = (const float*)d_in[18];
  const float* b2_mu = (const float*)d_in[19];

  float* out_u2 = (float*)d_out;                       // [NU,64]
  float* out_m2 = (float*)d_out + (size_t)NU * HDIM;   // [NM,64]

  // workspace carve (256B aligned)
  char* ws = (char*)d_ws;
  size_t off = 0;
  auto carve = [&](size_t bytes) -> char* {
    char* p = ws + off;
    off = (off + bytes + 255) & ~(size_t)255;
    return p;
  };
  int* offm = (int*)carve((size_t)(NM + 1) * 4);
  int* offu = (int*)carve((size_t)(NU + 1) * 4);
  int* curm = (int*)carve((size_t)NM * 4);
  int* curu = (int*)carve((size_t)NU * 4);
  int* part = (int*)carve(256 * 4);
  int* csrm = (int*)carve((size_t)E * 4);  // user srcs bucketed by movie
  int* csru = (int*)carve((size_t)E * 4);  // movie srcs bucketed by user
  float* m1 = (float*)carve((size_t)NM * HDIM * 4);
  float* u1 = (float*)carve((size_t)NU * HDIM * 4);
  (void)ws_size;

  const int TB = 256;
  int gridE = 2048;

  // 1) counts
  k_zero2<<<512, TB, 0, stream>>>(curm, NM, curu, NU);
  k_count<<<gridE, TB, 0, stream>>>(dst_um, dst_mu, curm, curu, E);

  // 2) exclusive scans -> offsets
  int nbm = (NM + 1023) / 1024;
  int nbu = (NU + 1023) / 1024;
  k_block_sum<<<nbm, TB, 0, stream>>>(curm, part, NM);
  k_scan_part<<<1, TB, 0, stream>>>(part, nbm);
  k_scan_final<<<nbm, TB, 0, stream>>>(curm, part, offm, NM);
  k_block_sum<<<nbu, TB, 0, stream>>>(curu, part, NU);
  k_scan_part<<<1, TB, 0, stream>>>(part, nbu);
  k_scan_final<<<nbu, TB, 0, stream>>>(curu, part, offu, NU);
  k_settotal<<<1, 64, 0, stream>>>(offm + NM, offu + NU, E);

  // 3) fill CSR
  k_zero2<<<512, TB, 0, stream>>>(curm, NM, curu, NU);
  k_fill<<<gridE, TB, 0, stream>>>(src_um, dst_um, src_mu, dst_mu,
                                   offm, offu, curm, curu, csrm, csru, E);

  // 4) layer 1 (relu)
  int gm = 2048, gu = 2048;
  k_sage<<<gm, TB, 0, stream>>>(user_table, movie_table, offm, csrm,
                                Wl1_um, Wr1_um, b1_um, m1, NM, 1);
  k_sage<<<gu, TB, 0, stream>>>(movie_table, user_table, offu, csru,
                                Wl1_mu, Wr1_mu, b1_mu, u1, NU, 1);

  // 5) layer 2 (no relu) -> outputs
  k_sage<<<gm, TB, 0, stream>>>(u1, m1, offm, csrm,
                                Wl2_um, Wr2_um, b2_um, out_m2, NM, 0);
  k_sage<<<gu, TB, 0, stream>>>(m1, u1, offu, csru,
                                Wl2_mu, Wr2_mu, b2_mu, out_u2, NU, 0);
}

// Round 3
// 874.368 us; speedup vs baseline: 3.1848x; 1.2775x over previous
//
#include <hip/hip_runtime.h>

#define HDIM 64

// ---------------- CSR build helpers ----------------

__global__ void k_zero2(int* __restrict__ a, int na, int* __restrict__ b, int nb) {
  int i = blockIdx.x * blockDim.x + threadIdx.x;
  int stride = gridDim.x * blockDim.x;
  for (int j = i; j < na; j += stride) a[j] = 0;
  for (int j = i; j < nb; j += stride) b[j] = 0;
}

__global__ void k_count(const int* __restrict__ dum, const int* __restrict__ dmu,
                        int* __restrict__ cm, int* __restrict__ cu, int E) {
  int i = blockIdx.x * blockDim.x + threadIdx.x;
  int stride = gridDim.x * blockDim.x;
  for (int e = i; e < E; e += stride) {
    atomicAdd(&cm[dum[e]], 1);
    atomicAdd(&cu[dmu[e]], 1);
  }
}

// block b sums in[b*1024 .. b*1024+1023] -> part[b]
__global__ void k_block_sum(const int* __restrict__ in, int* __restrict__ part, int n) {
  __shared__ int s[256];
  int b = blockIdx.x, t = threadIdx.x;
  int base = b * 1024;
  int v = 0;
  for (int i = t; i < 1024; i += 256) {
    int idx = base + i;
    if (idx < n) v += in[idx];
  }
  s[t] = v;
  __syncthreads();
  for (int o = 128; o > 0; o >>= 1) {
    if (t < o) s[t] += s[t + o];
    __syncthreads();
  }
  if (t == 0) part[b] = s[0];
}

// single block, nb <= 256: exclusive scan of part[]
__global__ void k_scan_part(int* __restrict__ part, int nb) {
  __shared__ int s[256];
  int t = threadIdx.x;
  int v = (t < nb) ? part[t] : 0;
  s[t] = v;
  __syncthreads();
  for (int o = 1; o < 256; o <<= 1) {
    int u = (t >= o) ? s[t - o] : 0;
    __syncthreads();
    s[t] += u;
    __syncthreads();
  }
  if (t < nb) part[t] = s[t] - v;  // exclusive
}

// block b: exclusive scan of its 1024-chunk + part[b] offset -> out
__global__ void k_scan_final(const int* __restrict__ in, const int* __restrict__ part,
                             int* __restrict__ out, int n) {
  __shared__ int s[256];
  int b = blockIdx.x, t = threadIdx.x;
  int base = b * 1024 + t * 4;
  int a[4];
#pragma unroll
  for (int i = 0; i < 4; i++) a[i] = (base + i < n) ? in[base + i] : 0;
  int tsum = a[0] + a[1] + a[2] + a[3];
  s[t] = tsum;
  __syncthreads();
  for (int o = 1; o < 256; o <<= 1) {
    int u = (t >= o) ? s[t - o] : 0;
    __syncthreads();
    s[t] += u;
    __syncthreads();
  }
  int excl = s[t] - tsum + part[b];
#pragma unroll
  for (int i = 0; i < 4; i++) {
    if (base + i < n) out[base + i] = excl;
    excl += a[i];
  }
}

__global__ void k_settotal(int* __restrict__ pm, int* __restrict__ pu, int E) {
  if (threadIdx.x == 0 && blockIdx.x == 0) { *pm = E; *pu = E; }
}

__global__ void k_fill(const int* __restrict__ sum_, const int* __restrict__ dum,
                       const int* __restrict__ smu, const int* __restrict__ dmu,
                       const int* __restrict__ offm, const int* __restrict__ offu,
                       int* __restrict__ curm, int* __restrict__ curu,
                       int* __restrict__ csrm, int* __restrict__ csru, int E) {
  int i = blockIdx.x * blockDim.x + threadIdx.x;
  int stride = gridDim.x * blockDim.x;
  for (int e = i; e < E; e += stride) {
    int d = dum[e];
    int p = atomicAdd(&curm[d], 1);
    csrm[offm[d] + p] = sum_[e];
    int d2 = dmu[e];
    int p2 = atomicAdd(&curu[d2], 1);
    csru[offu[d2] + p2] = smu[e];
  }
}

// ---------------- aggregation: mean over CSR neighbors ----------------
// 16-lane group per node; lane q holds cols 4q..4q+3 (float4).
// No LDS, low VGPR -> 8 waves/SIMD; deep unroll for outstanding loads.
__global__ __launch_bounds__(256) void k_agg(const float* __restrict__ xsrc,
                                             const int* __restrict__ offs,
                                             const int* __restrict__ csr,
                                             float* __restrict__ agg,
                                             int n_dst) {
  int t = threadIdx.x;
  int q = t & 15;
  int gg = (blockIdx.x * 256 + t) >> 4;
  int stride = (gridDim.x * 256) >> 4;

  for (int node = gg; node < n_dst; node += stride) {
    int beg = offs[node];
    int end = offs[node + 1];
    float4 a = make_float4(0.f, 0.f, 0.f, 0.f);
    int e = beg;
    for (; e + 4 <= end; e += 4) {
      int i0 = csr[e];
      int i1 = csr[e + 1];
      int i2 = csr[e + 2];
      int i3 = csr[e + 3];
      float4 v0 = *(const float4*)&xsrc[(size_t)i0 * HDIM + 4 * q];
      float4 v1 = *(const float4*)&xsrc[(size_t)i1 * HDIM + 4 * q];
      float4 v2 = *(const float4*)&xsrc[(size_t)i2 * HDIM + 4 * q];
      float4 v3 = *(const float4*)&xsrc[(size_t)i3 * HDIM + 4 * q];
      a.x += v0.x + v1.x + v2.x + v3.x;
      a.y += v0.y + v1.y + v2.y + v3.y;
      a.z += v0.z + v1.z + v2.z + v3.z;
      a.w += v0.w + v1.w + v2.w + v3.w;
    }
    for (; e < end; ++e) {
      int i0 = csr[e];
      float4 v0 = *(const float4*)&xsrc[(size_t)i0 * HDIM + 4 * q];
      a.x += v0.x; a.y += v0.y; a.z += v0.z; a.w += v0.w;
    }
    int deg = end - beg;
    float inv = deg > 0 ? 1.f / (float)deg : 0.f;
    a.x *= inv; a.y *= inv; a.z *= inv; a.w *= inv;
    *(float4*)&agg[(size_t)node * HDIM + 4 * q] = a;
  }
}

// component select with compile-time c (folds under #pragma unroll)
__device__ __forceinline__ float f4c(const float4& v, int c) {
  return c == 0 ? v.x : c == 1 ? v.y : c == 2 ? v.z : v.w;
}

// ---------------- transform: out = A@Wl + X@Wr + b (opt relu) ----------------
// 8 nodes per 64-lane wave (2 per 16-lane group). h rows split across groups
// (group g covers h in [16g,16g+16)); partials butterfly-reduced over groups.
// W is read from LDS exactly once per 8 nodes.
__global__ __launch_bounds__(256) void k_xform(const float* __restrict__ A,
                                               const float* __restrict__ X,
                                               const float* __restrict__ Wl,
                                               const float* __restrict__ Wr,
                                               const float* __restrict__ bias,
                                               float* __restrict__ out,
                                               int n_dst, int do_relu) {
  __shared__ float sW[2 * HDIM * HDIM];    // Wl | Wr, 32 KB
  __shared__ float sAX[4][2][8][HDIM];     // [wave][a|x][slot][col], 16 KB

  int t = threadIdx.x;
  {
    const float4* wl4 = (const float4*)Wl;
    const float4* wr4 = (const float4*)Wr;
    float4* s4 = (float4*)sW;
    for (int i = t; i < HDIM * HDIM / 4; i += 256) {
      s4[i] = wl4[i];
      s4[HDIM * HDIM / 4 + i] = wr4[i];
    }
  }
  __syncthreads();

  int lane = t & 63;
  int w = t >> 6;
  int q = lane & 15;
  int g = lane >> 4;
  float4 bj = *(const float4*)&bias[4 * q];

  int wid = blockIdx.x * 4 + w;
  int nw = gridDim.x * 4;

  for (int base = 8 * wid; base < n_dst; base += 8 * nw) {
    // ---- stage a,x rows for slots g and 4+g ----
    int na = base + g;        // slot g
    int nb = base + 4 + g;    // slot 4+g
    float4 z = make_float4(0.f, 0.f, 0.f, 0.f);
    float4 aA = z, xA = z, aB = z, xB = z;
    if (na < n_dst) {
      aA = *(const float4*)&A[(size_t)na * HDIM + 4 * q];
      xA = *(const float4*)&X[(size_t)na * HDIM + 4 * q];
    }
    if (nb < n_dst) {
      aB = *(const float4*)&A[(size_t)nb * HDIM + 4 * q];
      xB = *(const float4*)&X[(size_t)nb * HDIM + 4 * q];
    }
    *(float4*)&sAX[w][0][g][4 * q] = aA;
    *(float4*)&sAX[w][1][g][4 * q] = xA;
    *(float4*)&sAX[w][0][4 + g][4 * q] = aB;
    *(float4*)&sAX[w][1][4 + g][4 * q] = xB;
    // same-wave LDS producer/consumer: compiler inserts lgkmcnt waits

    float4 o[8];
#pragma unroll
    for (int s = 0; s < 8; ++s) o[s] = z;

#pragma unroll
    for (int hq = 0; hq < 4; ++hq) {
      int hbase = 16 * g + 4 * hq;
      float4 wl[4], wr[4];
#pragma unroll
      for (int c = 0; c < 4; ++c) {
        wl[c] = *(const float4*)&sW[(hbase + c) * HDIM + 4 * q];
        wr[c] = *(const float4*)&sW[HDIM * HDIM + (hbase + c) * HDIM + 4 * q];
      }
#pragma unroll
      for (int s = 0; s < 8; ++s) {
        float4 av = *(const float4*)&sAX[w][0][s][hbase];
        float4 xv = *(const float4*)&sAX[w][1][s][hbase];
#pragma unroll
        for (int c = 0; c < 4; ++c) {
          float a1 = f4c(av, c), x1 = f4c(xv, c);
          o[s].x += a1 * wl[c].x + x1 * wr[c].x;
          o[s].y += a1 * wl[c].y + x1 * wr[c].y;
          o[s].z += a1 * wl[c].z + x1 * wr[c].z;
          o[s].w += a1 * wl[c].w + x1 * wr[c].w;
        }
      }
    }

    // ---- butterfly-reduce partials across the 4 groups ----
#pragma unroll
    for (int m = 16; m <= 32; m <<= 1) {
#pragma unroll
      for (int s = 0; s < 8; ++s) {
        o[s].x += __shfl_xor(o[s].x, m);
        o[s].y += __shfl_xor(o[s].y, m);
        o[s].z += __shfl_xor(o[s].z, m);
        o[s].w += __shfl_xor(o[s].w, m);
      }
    }

    // group g stores nodes base+2g, base+2g+1 (static reg indices per branch)
    float4 s0, s1;
    if (g == 0)      { s0 = o[0]; s1 = o[1]; }
    else if (g == 1) { s0 = o[2]; s1 = o[3]; }
    else if (g == 2) { s0 = o[4]; s1 = o[5]; }
    else             { s0 = o[6]; s1 = o[7]; }
    int n0 = base + 2 * g;
    int n1 = base + 2 * g + 1;
    s0.x += bj.x; s0.y += bj.y; s0.z += bj.z; s0.w += bj.w;
    s1.x += bj.x; s1.y += bj.y; s1.z += bj.z; s1.w += bj.w;
    if (do_relu) {
      s0.x = fmaxf(s0.x, 0.f); s0.y = fmaxf(s0.y, 0.f);
      s0.z = fmaxf(s0.z, 0.f); s0.w = fmaxf(s0.w, 0.f);
      s1.x = fmaxf(s1.x, 0.f); s1.y = fmaxf(s1.y, 0.f);
      s1.z = fmaxf(s1.z, 0.f); s1.w = fmaxf(s1.w, 0.f);
    }
    if (n0 < n_dst) *(float4*)&out[(size_t)n0 * HDIM + 4 * q] = s0;
    if (n1 < n_dst) *(float4*)&out[(size_t)n1 * HDIM + 4 * q] = s1;
  }
}

// ---------------- launch ----------------

static inline int imin(int a, int b) { return a < b ? a : b; }

extern "C" void kernel_launch(void* const* d_in, const int* in_sizes, int n_in,
                              void* d_out, int out_size, void* d_ws, size_t ws_size,
                              hipStream_t stream) {
  const int NU = in_sizes[0];
  const int NM = in_sizes[1];
  const int E  = in_sizes[2];

  const int* src_um = (const int*)d_in[2];
  const int* dst_um = (const int*)d_in[3];
  const int* src_mu = (const int*)d_in[4];
  const int* dst_mu = (const int*)d_in[5];
  const float* user_table  = (const float*)d_in[6];
  const float* movie_table = (const float*)d_in[7];
  const float* Wl1_um = (const float*)d_in[8];
  const float* Wr1_um = (const float*)d_in[9];
  const float* Wl1_mu = (const float*)d_in[10];
  const float* Wr1_mu = (const float*)d_in[11];
  const float* Wl2_um = (const float*)d_in[12];
  const float* Wr2_um = (const float*)d_in[13];
  const float* Wl2_mu = (const float*)d_in[14];
  const float* Wr2_mu = (const float*)d_in[15];
  const float* b1_um = (const float*)d_in[16];
  const float* b1_mu = (const float*)d_in[17];
  const float* b2_um = (const float*)d_in[18];
  const float* b2_mu = (const float*)d_in[19];

  float* out_u2 = (float*)d_out;                       // [NU,64]
  float* out_m2 = (float*)d_out + (size_t)NU * HDIM;   // [NM,64]
  // agg scratch lives in d_out (layer2 xform is per-row in-place)
  float* aggu = out_u2;
  float* aggm = out_m2;

  // workspace carve (256B aligned)
  char* ws = (char*)d_ws;
  size_t off = 0;
  auto carve = [&](size_t bytes) -> char* {
    char* p = ws + off;
    off = (off + bytes + 255) & ~(size_t)255;
    return p;
  };
  int* offm = (int*)carve((size_t)(NM + 1) * 4);
  int* offu = (int*)carve((size_t)(NU + 1) * 4);
  int* curm = (int*)carve((size_t)NM * 4);
  int* curu = (int*)carve((size_t)NU * 4);
  int* part = (int*)carve(256 * 4);
  int* csrm = (int*)carve((size_t)E * 4);  // user srcs bucketed by movie
  int* csru = (int*)carve((size_t)E * 4);  // movie srcs bucketed by user
  float* m1 = (float*)carve((size_t)NM * HDIM * 4);
  float* u1 = (float*)carve((size_t)NU * HDIM * 4);
  (void)ws_size;

  const int TB = 256;
  int gridE = 2048;

  // 1) counts
  k_zero2<<<512, TB, 0, stream>>>(curm, NM, curu, NU);
  k_count<<<gridE, TB, 0, stream>>>(dst_um, dst_mu, curm, curu, E);

  // 2) exclusive scans -> offsets
  int nbm = (NM + 1023) / 1024;
  int nbu = (NU + 1023) / 1024;
  k_block_sum<<<nbm, TB, 0, stream>>>(curm, part, NM);
  k_scan_part<<<1, TB, 0, stream>>>(part, nbm);
  k_scan_final<<<nbm, TB, 0, stream>>>(curm, part, offm, NM);
  k_block_sum<<<nbu, TB, 0, stream>>>(curu, part, NU);
  k_scan_part<<<1, TB, 0, stream>>>(part, nbu);
  k_scan_final<<<nbu, TB, 0, stream>>>(curu, part, offu, NU);
  k_settotal<<<1, 64, 0, stream>>>(offm + NM, offu + NU, E);

  // 3) fill CSR
  k_zero2<<<512, TB, 0, stream>>>(curm, NM, curu, NU);
  k_fill<<<gridE, TB, 0, stream>>>(src_um, dst_um, src_mu, dst_mu,
                                   offm, offu, curm, curu, csrm, csru, E);

  int gAm = imin((NM + 15) / 16, 4096);
  int gAu = imin((NU + 15) / 16, 4096);
  int gXm = imin((NM + 31) / 32, 1024);
  int gXu = imin((NU + 31) / 32, 1024);

  // 4) layer 1 (relu): agg into d_out scratch, xform into ws (m1,u1)
  k_agg<<<gAm, TB, 0, stream>>>(user_table, offm, csrm, aggm, NM);
  k_agg<<<gAu, TB, 0, stream>>>(movie_table, offu, csru, aggu, NU);
  k_xform<<<gXm, TB, 0, stream>>>(aggm, movie_table, Wl1_um, Wr1_um, b1_um,
                                  m1, NM, 1);
  k_xform<<<gXu, TB, 0, stream>>>(aggu, user_table, Wl1_mu, Wr1_mu, b1_mu,
                                  u1, NU, 1);

  // 5) layer 2 (no relu): agg into d_out, xform in-place (per-row) -> d_out
  k_agg<<<gAm, TB, 0, stream>>>(u1, offm, csrm, aggm, NM);
  k_agg<<<gAu, TB, 0, stream>>>(m1, offu, csru, aggu, NU);
  k_xform<<<gXm, TB, 0, stream>>>(aggm, m1, Wl2_um, Wr2_um, b2_um,
                                  out_m2, NM, 0);
  k_xform<<<gXu, TB, 0, stream>>>(aggu, u1, Wl2_mu, Wr2_mu, b2_mu,
                                  out_u2, NU, 0);
}

// Round 4
// 735.490 us; speedup vs baseline: 3.7862x; 1.1888x over previous
//
#include <hip/hip_runtime.h>

#define HDIM 64

// ---------------- bf16 helpers ----------------
__device__ __forceinline__ float bf2f(unsigned short u) {
  unsigned int x = ((unsigned int)u) << 16;
  return __uint_as_float(x);
}
__device__ __forceinline__ unsigned short f2bf(float f) {
  unsigned int x = __float_as_uint(f);
  unsigned int r = (x + 0x7FFFu + ((x >> 16) & 1u)) >> 16;  // RNE
  return (unsigned short)r;
}

// ---------------- CSR build helpers ----------------

__global__ void k_zero2(int* __restrict__ a, int na, int* __restrict__ b, int nb) {
  int i = blockIdx.x * blockDim.x + threadIdx.x;
  int stride = gridDim.x * blockDim.x;
  for (int j = i; j < na; j += stride) a[j] = 0;
  for (int j = i; j < nb; j += stride) b[j] = 0;
}

__global__ void k_count(const int* __restrict__ dum, const int* __restrict__ dmu,
                        int* __restrict__ cm, int* __restrict__ cu, int E) {
  int i = blockIdx.x * blockDim.x + threadIdx.x;
  int stride = gridDim.x * blockDim.x;
  for (int e = i; e < E; e += stride) {
    atomicAdd(&cm[dum[e]], 1);
    atomicAdd(&cu[dmu[e]], 1);
  }
}

// block b sums in[b*1024 .. b*1024+1023] -> part[b]
__global__ void k_block_sum(const int* __restrict__ in, int* __restrict__ part, int n) {
  __shared__ int s[256];
  int b = blockIdx.x, t = threadIdx.x;
  int base = b * 1024;
  int v = 0;
  for (int i = t; i < 1024; i += 256) {
    int idx = base + i;
    if (idx < n) v += in[idx];
  }
  s[t] = v;
  __syncthreads();
  for (int o = 128; o > 0; o >>= 1) {
    if (t < o) s[t] += s[t + o];
    __syncthreads();
  }
  if (t == 0) part[b] = s[0];
}

// single block, nb <= 256: exclusive scan of part[]
__global__ void k_scan_part(int* __restrict__ part, int nb) {
  __shared__ int s[256];
  int t = threadIdx.x;
  int v = (t < nb) ? part[t] : 0;
  s[t] = v;
  __syncthreads();
  for (int o = 1; o < 256; o <<= 1) {
    int u = (t >= o) ? s[t - o] : 0;
    __syncthreads();
    s[t] += u;
    __syncthreads();
  }
  if (t < nb) part[t] = s[t] - v;  // exclusive
}

// block b: exclusive scan of its 1024-chunk + part[b] offset -> out
__global__ void k_scan_final(const int* __restrict__ in, const int* __restrict__ part,
                             int* __restrict__ out, int n) {
  __shared__ int s[256];
  int b = blockIdx.x, t = threadIdx.x;
  int base = b * 1024 + t * 4;
  int a[4];
#pragma unroll
  for (int i = 0; i < 4; i++) a[i] = (base + i < n) ? in[base + i] : 0;
  int tsum = a[0] + a[1] + a[2] + a[3];
  s[t] = tsum;
  __syncthreads();
  for (int o = 1; o < 256; o <<= 1) {
    int u = (t >= o) ? s[t - o] : 0;
    __syncthreads();
    s[t] += u;
    __syncthreads();
  }
  int excl = s[t] - tsum + part[b];
#pragma unroll
  for (int i = 0; i < 4; i++) {
    if (base + i < n) out[base + i] = excl;
    excl += a[i];
  }
}

__global__ void k_settotal(int* __restrict__ pm, int* __restrict__ pu, int E) {
  if (threadIdx.x == 0 && blockIdx.x == 0) { *pm = E; *pu = E; }
}

// XCD-partitioned CSR fill: blockIdx&7 selects an exclusive 1/8 dst range,
// so each XCD's L2 owns a small write window and lines fill before eviction.
// Every edge is handled by exactly one group -> correctness independent of
// the blockIdx->XCD mapping (that only affects locality).
__global__ __launch_bounds__(256) void k_fill_x(const int* __restrict__ src,
                                                const int* __restrict__ dst,
                                                const int* __restrict__ offs,
                                                int* __restrict__ cur,
                                                int* __restrict__ csr,
                                                int E, int n_dst) {
  int xg = blockIdx.x & 7;
  int lo = (n_dst * xg) >> 3;
  int hi = (n_dst * (xg + 1)) >> 3;
  if (xg == 7) hi = n_dst;
  int i = (blockIdx.x >> 3) * blockDim.x + threadIdx.x;
  int stride = (gridDim.x >> 3) * blockDim.x;
  for (int e = i; e < E; e += stride) {
    int d = dst[e];
    int s = src[e];
    if (d >= lo && d < hi) {
      int p = atomicAdd(&cur[d], 1);
      csr[offs[d] + p] = s;
    }
  }
}

// ---------------- fp32 -> bf16 conversion (8 elems/thread) ----------------
__global__ __launch_bounds__(256) void k_tobf16(const float* __restrict__ in,
                                                unsigned short* __restrict__ out,
                                                int n8) {
  int i = blockIdx.x * 256 + threadIdx.x;
  int stride = gridDim.x * 256;
  for (int j = i; j < n8; j += stride) {
    const float4* p = (const float4*)(in + (size_t)j * 8);
    float4 a = p[0], b = p[1];
    uint4 o;
    o.x = (unsigned int)f2bf(a.x) | ((unsigned int)f2bf(a.y) << 16);
    o.y = (unsigned int)f2bf(a.z) | ((unsigned int)f2bf(a.w) << 16);
    o.z = (unsigned int)f2bf(b.x) | ((unsigned int)f2bf(b.y) << 16);
    o.w = (unsigned int)f2bf(b.z) | ((unsigned int)f2bf(b.w) << 16);
    *(uint4*)(out + (size_t)j * 8) = o;
  }
}

// ---------------- aggregation: mean over CSR neighbors (bf16 src) ----------------
// 16-lane group per node; lane q holds cols 4q..4q+3 (8B ushort4 per row).
__global__ __launch_bounds__(256) void k_agg_bf(const unsigned short* __restrict__ xsrc,
                                                const int* __restrict__ offs,
                                                const int* __restrict__ csr,
                                                float* __restrict__ agg,
                                                int n_dst) {
  int t = threadIdx.x;
  int q = t & 15;
  int gg = (blockIdx.x * 256 + t) >> 4;
  int stride = (gridDim.x * 256) >> 4;

  for (int node = gg; node < n_dst; node += stride) {
    int beg = offs[node];
    int end = offs[node + 1];
    float4 a = make_float4(0.f, 0.f, 0.f, 0.f);
    int e = beg;
    for (; e + 4 <= end; e += 4) {
      int i0 = csr[e];
      int i1 = csr[e + 1];
      int i2 = csr[e + 2];
      int i3 = csr[e + 3];
      ushort4 v0 = *(const ushort4*)&xsrc[(size_t)i0 * HDIM + 4 * q];
      ushort4 v1 = *(const ushort4*)&xsrc[(size_t)i1 * HDIM + 4 * q];
      ushort4 v2 = *(const ushort4*)&xsrc[(size_t)i2 * HDIM + 4 * q];
      ushort4 v3 = *(const ushort4*)&xsrc[(size_t)i3 * HDIM + 4 * q];
      a.x += bf2f(v0.x) + bf2f(v1.x) + bf2f(v2.x) + bf2f(v3.x);
      a.y += bf2f(v0.y) + bf2f(v1.y) + bf2f(v2.y) + bf2f(v3.y);
      a.z += bf2f(v0.z) + bf2f(v1.z) + bf2f(v2.z) + bf2f(v3.z);
      a.w += bf2f(v0.w) + bf2f(v1.w) + bf2f(v2.w) + bf2f(v3.w);
    }
    for (; e < end; ++e) {
      int i0 = csr[e];
      ushort4 v0 = *(const ushort4*)&xsrc[(size_t)i0 * HDIM + 4 * q];
      a.x += bf2f(v0.x); a.y += bf2f(v0.y);
      a.z += bf2f(v0.z); a.w += bf2f(v0.w);
    }
    int deg = end - beg;
    float inv = deg > 0 ? 1.f / (float)deg : 0.f;
    a.x *= inv; a.y *= inv; a.z *= inv; a.w *= inv;
    *(float4*)&agg[(size_t)node * HDIM + 4 * q] = a;
  }
}

// component select with compile-time c (folds under #pragma unroll)
__device__ __forceinline__ float f4c(const float4& v, int c) {
  return c == 0 ? v.x : c == 1 ? v.y : c == 2 ? v.z : v.w;
}

// ---------------- transform: out = A@Wl + X@Wr + b (opt relu) ----------------
// 8 nodes per 64-lane wave (2 per 16-lane group). h rows split across groups
// (group g covers h in [16g,16g+16)); partials butterfly-reduced over groups.
// W is read from LDS exactly once per 8 nodes.
// XBF: X input is bf16. OUTBF: output stored as bf16.
template <int XBF, int OUTBF>
__global__ __launch_bounds__(256) void k_xform(const float* __restrict__ A,
                                               const void* __restrict__ Xv,
                                               const float* __restrict__ Wl,
                                               const float* __restrict__ Wr,
                                               const float* __restrict__ bias,
                                               void* __restrict__ outv,
                                               int n_dst, int do_relu) {
  __shared__ float sW[2 * HDIM * HDIM];    // Wl | Wr, 32 KB
  __shared__ float sAX[4][2][8][HDIM];     // [wave][a|x][slot][col], 16 KB

  int t = threadIdx.x;
  {
    const float4* wl4 = (const float4*)Wl;
    const float4* wr4 = (const float4*)Wr;
    float4* s4 = (float4*)sW;
    for (int i = t; i < HDIM * HDIM / 4; i += 256) {
      s4[i] = wl4[i];
      s4[HDIM * HDIM / 4 + i] = wr4[i];
    }
  }
  __syncthreads();

  int lane = t & 63;
  int w = t >> 6;
  int q = lane & 15;
  int g = lane >> 4;
  float4 bj = *(const float4*)&bias[4 * q];

  int wid = blockIdx.x * 4 + w;
  int nw = gridDim.x * 4;

  for (int base = 8 * wid; base < n_dst; base += 8 * nw) {
    // ---- stage a,x rows for slots g and 4+g ----
    int na = base + g;        // slot g
    int nb = base + 4 + g;    // slot 4+g
    float4 z = make_float4(0.f, 0.f, 0.f, 0.f);
    float4 aA = z, xA = z, aB = z, xB = z;
    if (na < n_dst) {
      aA = *(const float4*)&A[(size_t)na * HDIM + 4 * q];
      if (XBF) {
        ushort4 v = *(const ushort4*)((const unsigned short*)Xv + (size_t)na * HDIM + 4 * q);
        xA = make_float4(bf2f(v.x), bf2f(v.y), bf2f(v.z), bf2f(v.w));
      } else {
        xA = *(const float4*)((const float*)Xv + (size_t)na * HDIM + 4 * q);
      }
    }
    if (nb < n_dst) {
      aB = *(const float4*)&A[(size_t)nb * HDIM + 4 * q];
      if (XBF) {
        ushort4 v = *(const ushort4*)((const unsigned short*)Xv + (size_t)nb * HDIM + 4 * q);
        xB = make_float4(bf2f(v.x), bf2f(v.y), bf2f(v.z), bf2f(v.w));
      } else {
        xB = *(const float4*)((const float*)Xv + (size_t)nb * HDIM + 4 * q);
      }
    }
    *(float4*)&sAX[w][0][g][4 * q] = aA;
    *(float4*)&sAX[w][1][g][4 * q] = xA;
    *(float4*)&sAX[w][0][4 + g][4 * q] = aB;
    *(float4*)&sAX[w][1][4 + g][4 * q] = xB;
    // same-wave LDS producer/consumer: compiler inserts lgkmcnt waits

    float4 o[8];
#pragma unroll
    for (int s = 0; s < 8; ++s) o[s] = z;

#pragma unroll
    for (int hq = 0; hq < 4; ++hq) {
      int hbase = 16 * g + 4 * hq;
      float4 wl[4], wr[4];
#pragma unroll
      for (int c = 0; c < 4; ++c) {
        wl[c] = *(const float4*)&sW[(hbase + c) * HDIM + 4 * q];
        wr[c] = *(const float4*)&sW[HDIM * HDIM + (hbase + c) * HDIM + 4 * q];
      }
#pragma unroll
      for (int s = 0; s < 8; ++s) {
        float4 av = *(const float4*)&sAX[w][0][s][hbase];
        float4 xv = *(const float4*)&sAX[w][1][s][hbase];
#pragma unroll
        for (int c = 0; c < 4; ++c) {
          float a1 = f4c(av, c), x1 = f4c(xv, c);
          o[s].x += a1 * wl[c].x + x1 * wr[c].x;
          o[s].y += a1 * wl[c].y + x1 * wr[c].y;
          o[s].z += a1 * wl[c].z + x1 * wr[c].z;
          o[s].w += a1 * wl[c].w + x1 * wr[c].w;
        }
      }
    }

    // ---- butterfly-reduce partials across the 4 groups ----
#pragma unroll
    for (int m = 16; m <= 32; m <<= 1) {
#pragma unroll
      for (int s = 0; s < 8; ++s) {
        o[s].x += __shfl_xor(o[s].x, m);
        o[s].y += __shfl_xor(o[s].y, m);
        o[s].z += __shfl_xor(o[s].z, m);
        o[s].w += __shfl_xor(o[s].w, m);
      }
    }

    // group g stores nodes base+2g, base+2g+1 (static reg indices per branch)
    float4 s0, s1;
    if (g == 0)      { s0 = o[0]; s1 = o[1]; }
    else if (g == 1) { s0 = o[2]; s1 = o[3]; }
    else if (g == 2) { s0 = o[4]; s1 = o[5]; }
    else             { s0 = o[6]; s1 = o[7]; }
    int n0 = base + 2 * g;
    int n1 = base + 2 * g + 1;
    s0.x += bj.x; s0.y += bj.y; s0.z += bj.z; s0.w += bj.w;
    s1.x += bj.x; s1.y += bj.y; s1.z += bj.z; s1.w += bj.w;
    if (do_relu) {
      s0.x = fmaxf(s0.x, 0.f); s0.y = fmaxf(s0.y, 0.f);
      s0.z = fmaxf(s0.z, 0.f); s0.w = fmaxf(s0.w, 0.f);
      s1.x = fmaxf(s1.x, 0.f); s1.y = fmaxf(s1.y, 0.f);
      s1.z = fmaxf(s1.z, 0.f); s1.w = fmaxf(s1.w, 0.f);
    }
    if (OUTBF) {
      unsigned short* ob = (unsigned short*)outv;
      if (n0 < n_dst) {
        ushort4 r = make_ushort4(f2bf(s0.x), f2bf(s0.y), f2bf(s0.z), f2bf(s0.w));
        *(ushort4*)&ob[(size_t)n0 * HDIM + 4 * q] = r;
      }
      if (n1 < n_dst) {
        ushort4 r = make_ushort4(f2bf(s1.x), f2bf(s1.y), f2bf(s1.z), f2bf(s1.w));
        *(ushort4*)&ob[(size_t)n1 * HDIM + 4 * q] = r;
      }
    } else {
      float* of = (float*)outv;
      if (n0 < n_dst) *(float4*)&of[(size_t)n0 * HDIM + 4 * q] = s0;
      if (n1 < n_dst) *(float4*)&of[(size_t)n1 * HDIM + 4 * q] = s1;
    }
  }
}

// ---------------- launch ----------------

static inline int imin(int a, int b) { return a < b ? a : b; }

extern "C" void kernel_launch(void* const* d_in, const int* in_sizes, int n_in,
                              void* d_out, int out_size, void* d_ws, size_t ws_size,
                              hipStream_t stream) {
  const int NU = in_sizes[0];
  const int NM = in_sizes[1];
  const int E  = in_sizes[2];

  const int* src_um = (const int*)d_in[2];
  const int* dst_um = (const int*)d_in[3];
  const int* src_mu = (const int*)d_in[4];
  const int* dst_mu = (const int*)d_in[5];
  const float* user_table  = (const float*)d_in[6];
  const float* movie_table = (const float*)d_in[7];
  const float* Wl1_um = (const float*)d_in[8];
  const float* Wr1_um = (const float*)d_in[9];
  const float* Wl1_mu = (const float*)d_in[10];
  const float* Wr1_mu = (const float*)d_in[11];
  const float* Wl2_um = (const float*)d_in[12];
  const float* Wr2_um = (const float*)d_in[13];
  const float* Wl2_mu = (const float*)d_in[14];
  const float* Wr2_mu = (const float*)d_in[15];
  const float* b1_um = (const float*)d_in[16];
  const float* b1_mu = (const float*)d_in[17];
  const float* b2_um = (const float*)d_in[18];
  const float* b2_mu = (const float*)d_in[19];

  float* out_u2 = (float*)d_out;                       // [NU,64]
  float* out_m2 = (float*)d_out + (size_t)NU * HDIM;   // [NM,64]
  // agg scratch lives in d_out (layer2 xform is per-row in-place)
  float* aggu = out_u2;
  float* aggm = out_m2;

  // workspace carve (256B aligned)
  char* ws = (char*)d_ws;
  size_t off = 0;
  auto carve = [&](size_t bytes) -> char* {
    char* p = ws + off;
    off = (off + bytes + 255) & ~(size_t)255;
    return p;
  };
  int* offm = (int*)carve((size_t)(NM + 1) * 4);
  int* offu = (int*)carve((size_t)(NU + 1) * 4);
  int* curm = (int*)carve((size_t)NM * 4);
  int* curu = (int*)carve((size_t)NU * 4);
  int* part = (int*)carve(256 * 4);
  int* csrm = (int*)carve((size_t)E * 4);  // user srcs bucketed by movie
  int* csru = (int*)carve((size_t)E * 4);  // movie srcs bucketed by user
  unsigned short* m1b = (unsigned short*)carve((size_t)NM * HDIM * 2);
  unsigned short* u1b = (unsigned short*)carve((size_t)NU * HDIM * 2);
  unsigned short* mtb = (unsigned short*)carve((size_t)NM * HDIM * 2);
  unsigned short* utb = (unsigned short*)carve((size_t)NU * HDIM * 2);
  (void)ws_size;

  const int TB = 256;
  int gridE = 2048;

  // 0) bf16 copies of the embedding tables (gather operands)
  int n8u = NU * HDIM / 8, n8m = NM * HDIM / 8;
  k_tobf16<<<imin((n8u + 255) / 256, 2048), TB, 0, stream>>>(user_table, utb, n8u);
  k_tobf16<<<imin((n8m + 255) / 256, 2048), TB, 0, stream>>>(movie_table, mtb, n8m);

  // 1) counts
  k_zero2<<<512, TB, 0, stream>>>(curm, NM, curu, NU);
  k_count<<<gridE, TB, 0, stream>>>(dst_um, dst_mu, curm, curu, E);

  // 2) exclusive scans -> offsets
  int nbm = (NM + 1023) / 1024;
  int nbu = (NU + 1023) / 1024;
  k_block_sum<<<nbm, TB, 0, stream>>>(curm, part, NM);
  k_scan_part<<<1, TB, 0, stream>>>(part, nbm);
  k_scan_final<<<nbm, TB, 0, stream>>>(curm, part, offm, NM);
  k_block_sum<<<nbu, TB, 0, stream>>>(curu, part, NU);
  k_scan_part<<<1, TB, 0, stream>>>(part, nbu);
  k_scan_final<<<nbu, TB, 0, stream>>>(curu, part, offu, NU);
  k_settotal<<<1, 64, 0, stream>>>(offm + NM, offu + NU, E);

  // 3) fill CSR (XCD-partitioned dst ranges)
  k_zero2<<<512, TB, 0, stream>>>(curm, NM, curu, NU);
  k_fill_x<<<gridE, TB, 0, stream>>>(src_um, dst_um, offm, curm, csrm, E, NM);
  k_fill_x<<<gridE, TB, 0, stream>>>(src_mu, dst_mu, offu, curu, csru, E, NU);

  int gAm = imin((NM + 15) / 16, 4096);
  int gAu = imin((NU + 15) / 16, 4096);
  int gXm = imin((NM + 31) / 32, 1024);
  int gXu = imin((NU + 31) / 32, 1024);

  // 4) layer 1 (relu): agg (bf16 gather) into d_out scratch, xform -> bf16 ws
  k_agg_bf<<<gAm, TB, 0, stream>>>(utb, offm, csrm, aggm, NM);
  k_agg_bf<<<gAu, TB, 0, stream>>>(mtb, offu, csru, aggu, NU);
  k_xform<0, 1><<<gXm, TB, 0, stream>>>(aggm, movie_table, Wl1_um, Wr1_um, b1_um,
                                        m1b, NM, 1);
  k_xform<0, 1><<<gXu, TB, 0, stream>>>(aggu, user_table, Wl1_mu, Wr1_mu, b1_mu,
                                        u1b, NU, 1);

  // 5) layer 2 (no relu): agg (bf16 gather of u1/m1), xform in-place -> d_out
  k_agg_bf<<<gAm, TB, 0, stream>>>(u1b, offm, csrm, aggm, NM);
  k_agg_bf<<<gAu, TB, 0, stream>>>(m1b, offu, csru, aggu, NU);
  k_xform<1, 0><<<gXm, TB, 0, stream>>>(aggm, m1b, Wl2_um, Wr2_um, b2_um,
                                        out_m2, NM, 0);
  k_xform<1, 0><<<gXu, TB, 0, stream>>>(aggu, u1b, Wl2_mu, Wr2_mu, b2_mu,
                                        out_u2, NU, 0);
}